// Round 8
// baseline (588.394 us; speedup 1.0000x reference)
//
#include <hip/hip_runtime.h>
#include <math.h>

// ---------------------------------------------------------------------------
// SNAT3: 4-layer GAT GNN. N=50000, E=800000, HID=64, fp32.
// R15 = R14 dense kernels (verified 452us) + counting-sort CSR build.
//  R14 post-mortem: k_scatter WRITE_SIZE 52MB vs 3.2MB legit = one 64B line
//  writeback per edge (random 4B writes; dirty lines bounce across the 8
//  non-coherent per-XCD L2s before their 16 slots fill).
//  Fix (replaces k_scatter):
//   * k_hist2: counts[dst]++ AND coarse hist cntA[(dst>>7)*8+((e>>10)&7)]++
//   * k_scanA: exclusive scan of the 3128 (bucket,group) counters
//   * k_bin:   blocks append (src,dst) to their (bucket, blockIdx&7) region;
//              same-group blocks share an XCD -> frontier lines L2-local,
//              8 sequential 8B writes per line -> ~1x writeback (6.4MB).
//   * k_csr:   one block per bucket; row_ptr slice -> LDS cursors; scatter
//              ~2048 edges into the bucket's contiguous ~8KB csr range.
//  Edge order within a dst changes (was already atomic-race order); mask
//  indexing consistent within the launch. All dense kernels verbatim R14.
// ---------------------------------------------------------------------------

__global__ void k_zero(int* __restrict__ counts, int* __restrict__ cntA,
                       int N, int nbg) {
  int i = blockIdx.x * 256 + threadIdx.x;
  if (i < N) counts[i] = 0;
  if (i < nbg) cntA[i] = 0;
}

__global__ void k_hist2(const int* __restrict__ dst, int* __restrict__ counts,
                        int* __restrict__ cntA, int E) {
  int e = blockIdx.x * blockDim.x + threadIdx.x;
  if (e < E) {
    int d = dst[e];
    atomicAdd(&counts[d], 1);
    atomicAdd(&cntA[(d >> 7) * 8 + ((e >> 10) & 7)], 1);
  }
}

__global__ __launch_bounds__(1024) void k_bsum(const int* __restrict__ counts,
                                               int* __restrict__ bsum, int n) {
  __shared__ int wsum[16];
  int tid = threadIdx.x, lane = tid & 63, wid = tid >> 6;
  int i = blockIdx.x * 1024 + tid;
  int v = (i < n) ? counts[i] : 0;
  #pragma unroll
  for (int off = 32; off; off >>= 1) v += __shfl_xor(v, off, 64);
  if (lane == 0) wsum[wid] = v;
  __syncthreads();
  if (wid == 0) {
    int w = (lane < 16) ? wsum[lane] : 0;
    #pragma unroll
    for (int off = 8; off; off >>= 1) w += __shfl_xor(w, off, 64);
    if (lane == 0) bsum[blockIdx.x] = w;
  }
}

__global__ __launch_bounds__(64) void k_bscan(const int* __restrict__ bsum,
                                              int* __restrict__ bofs,
                                              int* __restrict__ row_ptr,
                                              int nb, int n) {
  int lane = threadIdx.x;
  int carry = 0;
  for (int base = 0; base < nb; base += 64) {
    int idx = base + lane;
    int orig = (idx < nb) ? bsum[idx] : 0;
    int inc = orig;
    #pragma unroll
    for (int off = 1; off < 64; off <<= 1) {
      int t = __shfl_up(inc, off, 64);
      if (lane >= off) inc += t;
    }
    if (idx < nb) bofs[idx] = carry + inc - orig;
    carry += __shfl(inc, 63, 64);
  }
  if (lane == 0) row_ptr[n] = carry;
}

__global__ __launch_bounds__(1024) void k_scan3(const int* __restrict__ counts,
                                                const int* __restrict__ bofs,
                                                int* __restrict__ row_ptr, int n) {
  __shared__ int wsum[16];
  int tid = threadIdx.x, lane = tid & 63, wid = tid >> 6;
  int i = blockIdx.x * 1024 + tid;
  int v = (i < n) ? counts[i] : 0;
  int inc = v;
  #pragma unroll
  for (int off = 1; off < 64; off <<= 1) {
    int t = __shfl_up(inc, off, 64);
    if (lane >= off) inc += t;
  }
  if (lane == 63) wsum[wid] = inc;
  __syncthreads();
  if (wid == 0 && lane < 16) {
    int orig = wsum[lane];
    int w = orig;
    #pragma unroll
    for (int off = 1; off < 16; off <<= 1) {
      int t = __shfl_up(w, off, 64);
      if (lane >= off) w += t;
    }
    wsum[lane] = w - orig;
  }
  __syncthreads();
  int excl = bofs[blockIdx.x] + wsum[wid] + inc - v;
  if (i < n) row_ptr[i] = excl;
}

// exclusive scan of the (bucket,group) histogram; also seeds running cursors
__global__ __launch_bounds__(64) void k_scanA(const int* __restrict__ cntA,
                                              int* __restrict__ ofsA,
                                              int* __restrict__ curA,
                                              int nbg, int E) {
  int lane = threadIdx.x;
  int carry = 0;
  for (int base = 0; base < nbg; base += 64) {
    int idx = base + lane;
    int orig = (idx < nbg) ? cntA[idx] : 0;
    int inc = orig;
    #pragma unroll
    for (int off = 1; off < 64; off <<= 1) {
      int t = __shfl_up(inc, off, 64);
      if (lane >= off) inc += t;
    }
    if (idx < nbg) {
      int ex = carry + inc - orig;
      ofsA[idx] = ex;
      curA[idx] = ex;
    }
    carry += __shfl(inc, 63, 64);
  }
  if (lane == 0) ofsA[nbg] = E;
}

// pass B: bin edges into (bucket, group) regions; group = blockIdx&7 = (e>>10)&7
__global__ __launch_bounds__(256) void k_bin(const int* __restrict__ src,
                                             const int* __restrict__ dst,
                                             int* __restrict__ curA,
                                             int2* __restrict__ tmp, int E) {
  int g = blockIdx.x & 7;
  int e0 = blockIdx.x * 1024 + threadIdx.x * 4;
  if (e0 >= E) return;
  if (e0 + 3 < E) {
    int4 s4 = *(const int4*)(src + e0);
    int4 d4 = *(const int4*)(dst + e0);
    int s[4] = {s4.x, s4.y, s4.z, s4.w};
    int d[4] = {d4.x, d4.y, d4.z, d4.w};
    #pragma unroll
    for (int i = 0; i < 4; i++) {
      int pos = atomicAdd(&curA[(d[i] >> 7) * 8 + g], 1);
      tmp[pos] = make_int2(s[i], d[i]);
    }
  } else {
    for (int i = 0; i < 4 && e0 + i < E; i++) {
      int sv = src[e0 + i], dv = dst[e0 + i];
      int pos = atomicAdd(&curA[(dv >> 7) * 8 + g], 1);
      tmp[pos] = make_int2(sv, dv);
    }
  }
}

// pass C: one block per bucket; LDS cursors for its 128 nodes; local scatter
__global__ __launch_bounds__(256) void k_csr(const int2* __restrict__ tmp,
                                             const int* __restrict__ ofsA,
                                             const int* __restrict__ row_ptr,
                                             int* __restrict__ csr_src,
                                             int N, int nbuk) {
  __shared__ int lcur[128];
  int b = blockIdx.x;
  int lo = b << 7;
  int hi = min(lo + 128, N);
  int tid = threadIdx.x;
  if (tid < hi - lo) lcur[tid] = row_ptr[lo + tid];
  __syncthreads();
  int beg = ofsA[b * 8];
  int end = ofsA[(b + 1) * 8];     // last bucket hits the E sentinel
  for (int i = beg + tid; i < end; i += 256) {
    int2 e = tmp[i];
    int pos = atomicAdd(&lcur[e.y - lo], 1);
    csr_src[pos] = e.x;
  }
}

// ---- dense building blocks ----
#define SWS 68   // sW float stride: rows 272B (16B-aligned) -> ds_read_b128

#define STAGE_W(DST, SRC)                                            \
  {                                                                  \
    int k_ = threadIdx.x >> 2, p_ = threadIdx.x & 3;                 \
    const float* s_ = (SRC) + k_ * 64 + p_ * 16;                     \
    float* d_ = (DST) + k_ * SWS + p_ * 16;                          \
    _Pragma("unroll")                                                \
    for (int c_ = 0; c_ < 4; c_++)                                   \
      *(float4*)(d_ + c_ * 4) = *(const float4*)(s_ + c_ * 4);       \
  }

#define GEMM64(ACC, ABASE, ASTRIDE, KOFF)                            \
  { _Pragma("unroll 4")                                              \
    for (int k_ = 0; k_ < 64; k_++) {                                \
      float4 w4_ = *(const float4*)&sW[k_ * SWS + fq];               \
      float a0_ = (ABASE)[(nr +  0) * (ASTRIDE) + (KOFF) + k_];      \
      float a1_ = (ABASE)[(nr + 16) * (ASTRIDE) + (KOFF) + k_];      \
      float a2_ = (ABASE)[(nr + 32) * (ASTRIDE) + (KOFF) + k_];      \
      float a3_ = (ABASE)[(nr + 48) * (ASTRIDE) + (KOFF) + k_];      \
      ACC[0][0] = fmaf(a0_, w4_.x, ACC[0][0]);                       \
      ACC[0][1] = fmaf(a0_, w4_.y, ACC[0][1]);                       \
      ACC[0][2] = fmaf(a0_, w4_.z, ACC[0][2]);                       \
      ACC[0][3] = fmaf(a0_, w4_.w, ACC[0][3]);                       \
      ACC[1][0] = fmaf(a1_, w4_.x, ACC[1][0]);                       \
      ACC[1][1] = fmaf(a1_, w4_.y, ACC[1][1]);                       \
      ACC[1][2] = fmaf(a1_, w4_.z, ACC[1][2]);                       \
      ACC[1][3] = fmaf(a1_, w4_.w, ACC[1][3]);                       \
      ACC[2][0] = fmaf(a2_, w4_.x, ACC[2][0]);                       \
      ACC[2][1] = fmaf(a2_, w4_.y, ACC[2][1]);                       \
      ACC[2][2] = fmaf(a2_, w4_.z, ACC[2][2]);                       \
      ACC[2][3] = fmaf(a2_, w4_.w, ACC[2][3]);                       \
      ACC[3][0] = fmaf(a3_, w4_.x, ACC[3][0]);                       \
      ACC[3][1] = fmaf(a3_, w4_.y, ACC[3][1]);                       \
      ACC[3][2] = fmaf(a3_, w4_.z, ACC[3][2]);                       \
      ACC[3][3] = fmaf(a3_, w4_.w, ACC[3][3]);                       \
    } }

// ---- fused: h = tanh(x@We); feat = h@Wg0; el/er.  h never hits global ----
__global__ __launch_bounds__(256, 3) void k_embed_feat(
    const float* __restrict__ x, const float* __restrict__ We,
    const float* __restrict__ Wg, const float* __restrict__ al,
    const float* __restrict__ ar, float* __restrict__ feat,
    float* __restrict__ el, float* __restrict__ er, int N) {
  __shared__ float sA[64 * 129];  // x staging (33KB); reused as 64x65 exchange
  __shared__ float sW[64 * SWS];  // weight slot: We-lo -> We-hi -> Wg
  __shared__ float sE[64 * 8];
  int tid = threadIdx.x, lane = tid & 63, wv = tid >> 6;
  int nb0 = blockIdx.x * 64, nl = N - 1;
  int r = tid >> 2, p = tid & 3;
  int nr = lane >> 2, fc = lane & 3;
  int fq = wv * 16 + fc * 4;
  {
    const float* gp = x + (size_t)min(nb0 + r, nl) * 128;
    #pragma unroll
    for (int half = 0; half < 2; half++) {
      const float* g = gp + half * 64 + p * 16;
      float4 v0 = *(const float4*)(g + 0), v1 = *(const float4*)(g + 4);
      float4 v2 = *(const float4*)(g + 8), v3 = *(const float4*)(g + 12);
      float* dp = &sA[r * 129 + half * 64 + p * 16];
      dp[0]=v0.x; dp[1]=v0.y; dp[2]=v0.z; dp[3]=v0.w;
      dp[4]=v1.x; dp[5]=v1.y; dp[6]=v1.z; dp[7]=v1.w;
      dp[8]=v2.x; dp[9]=v2.y; dp[10]=v2.z; dp[11]=v2.w;
      dp[12]=v3.x; dp[13]=v3.y; dp[14]=v3.z; dp[15]=v3.w;
    }
  }
  STAGE_W(sW, We);                 // We rows 0..63
  __syncthreads();
  float acc[4][4];
  #pragma unroll
  for (int m = 0; m < 4; m++)
    #pragma unroll
    for (int j = 0; j < 4; j++) acc[m][j] = 0.f;
  GEMM64(acc, sA, 129, 0);         // k 0..63
  __syncthreads();                 // GEMM1a sW reads done
  STAGE_W(sW, We + 4096);          // We rows 64..127
  __syncthreads();
  GEMM64(acc, sA, 129, 64);        // k 64..127
  __syncthreads();                 // x reads + GEMM1b sW reads done
  STAGE_W(sW, Wg);                 // Wg for the feat GEMM
  #pragma unroll
  for (int m = 0; m < 4; m++)
    #pragma unroll
    for (int j = 0; j < 4; j++)
      sA[(nr + 16 * m) * 65 + fq + j] = tanhf(acc[m][j]);
  __syncthreads();
  float acc2[4][4];
  #pragma unroll
  for (int m = 0; m < 4; m++)
    #pragma unroll
    for (int j = 0; j < 4; j++) acc2[m][j] = 0.f;
  GEMM64(acc2, sA, 65, 0);
  // el/er: 4-f dot per thread, quad tree over fc, fc==0 writes per node
  {
    float alv[4], arv[4];
    *(float4*)&alv[0] = *(const float4*)(al + fq);
    *(float4*)&arv[0] = *(const float4*)(ar + fq);
    #pragma unroll
    for (int m = 0; m < 4; m++) {
      float pl = 0.f, pr = 0.f;
      #pragma unroll
      for (int j = 0; j < 4; j++) {
        pl = fmaf(acc2[m][j], alv[j], pl);
        pr = fmaf(acc2[m][j], arv[j], pr);
      }
      pl += __shfl_xor(pl, 1, 64); pl += __shfl_xor(pl, 2, 64);
      pr += __shfl_xor(pr, 1, 64); pr += __shfl_xor(pr, 2, 64);
      if (fc == 0) {
        sE[(nr + 16 * m) * 8 + wv] = pl;
        sE[(nr + 16 * m) * 8 + 4 + wv] = pr;
      }
    }
  }
  __syncthreads();  // all GEMM2 sA reads done; safe to overwrite exchange
  #pragma unroll
  for (int m = 0; m < 4; m++)
    #pragma unroll
    for (int j = 0; j < 4; j++)
      sA[(nr + 16 * m) * 65 + fq + j] = acc2[m][j];
  __syncthreads();
  {
    int n = nb0 + r;
    if (n < N) {
      const float* sp = &sA[r * 65 + p * 16];
      float* gp = feat + (size_t)n * 64 + p * 16;
      #pragma unroll
      for (int q = 0; q < 4; q++)
        *(float4*)(gp + q * 4) = make_float4(sp[q*4+0], sp[q*4+1], sp[q*4+2], sp[q*4+3]);
    }
  }
  if (tid < 64) {
    int n = nb0 + tid;
    if (n < N) {
      el[n] = (sE[tid*8+0] + sE[tid*8+1]) + (sE[tid*8+2] + sE[tid*8+3]);
      er[n] = (sE[tid*8+4] + sE[tid*8+5]) + (sE[tid*8+6] + sE[tid*8+7]);
    }
  }
}

// ---- feat = hin @ Wg; el/er (layers 1..3) ----
__global__ __launch_bounds__(256, 3) void k_feat(const float* __restrict__ hin,
                                                 const float* __restrict__ Wg,
                                                 const float* __restrict__ al,
                                                 const float* __restrict__ ar,
                                                 float* __restrict__ feat,
                                                 float* __restrict__ el,
                                                 float* __restrict__ er, int N) {
  __shared__ float sA[64 * 65];
  __shared__ float sW[64 * SWS];
  __shared__ float sE[64 * 8];
  int tid = threadIdx.x, lane = tid & 63, wv = tid >> 6;
  int nb0 = blockIdx.x * 64;
  int nl = N - 1;
  int r = tid >> 2, p = tid & 3;
  int nr = lane >> 2, fc = lane & 3;
  int fq = wv * 16 + fc * 4;
  {
    const float* g = hin + (size_t)min(nb0 + r, nl) * 64 + p * 16;
    float4 v0 = *(const float4*)(g + 0), v1 = *(const float4*)(g + 4);
    float4 v2 = *(const float4*)(g + 8), v3 = *(const float4*)(g + 12);
    float* dp = &sA[r * 65 + p * 16];
    dp[0]=v0.x; dp[1]=v0.y; dp[2]=v0.z; dp[3]=v0.w;
    dp[4]=v1.x; dp[5]=v1.y; dp[6]=v1.z; dp[7]=v1.w;
    dp[8]=v2.x; dp[9]=v2.y; dp[10]=v2.z; dp[11]=v2.w;
    dp[12]=v3.x; dp[13]=v3.y; dp[14]=v3.z; dp[15]=v3.w;
  }
  STAGE_W(sW, Wg);
  __syncthreads();
  float acc[4][4];
  #pragma unroll
  for (int m = 0; m < 4; m++)
    #pragma unroll
    for (int j = 0; j < 4; j++) acc[m][j] = 0.f;
  GEMM64(acc, sA, 65, 0);
  // el/er partials
  {
    float alv[4], arv[4];
    *(float4*)&alv[0] = *(const float4*)(al + fq);
    *(float4*)&arv[0] = *(const float4*)(ar + fq);
    #pragma unroll
    for (int m = 0; m < 4; m++) {
      float pl = 0.f, pr = 0.f;
      #pragma unroll
      for (int j = 0; j < 4; j++) {
        pl = fmaf(acc[m][j], alv[j], pl);
        pr = fmaf(acc[m][j], arv[j], pr);
      }
      pl += __shfl_xor(pl, 1, 64); pl += __shfl_xor(pl, 2, 64);
      pr += __shfl_xor(pr, 1, 64); pr += __shfl_xor(pr, 2, 64);
      if (fc == 0) {
        sE[(nr + 16 * m) * 8 + wv] = pl;
        sE[(nr + 16 * m) * 8 + 4 + wv] = pr;
      }
    }
  }
  __syncthreads();  // all GEMM sA reads done; safe to overwrite exchange
  #pragma unroll
  for (int m = 0; m < 4; m++)
    #pragma unroll
    for (int j = 0; j < 4; j++)
      sA[(nr + 16 * m) * 65 + fq + j] = acc[m][j];
  __syncthreads();
  {
    int n = nb0 + r;
    if (n < N) {
      const float* sp = &sA[r * 65 + p * 16];
      float* gp = feat + (size_t)n * 64 + p * 16;
      #pragma unroll
      for (int q = 0; q < 4; q++)
        *(float4*)(gp + q * 4) = make_float4(sp[q*4+0], sp[q*4+1], sp[q*4+2], sp[q*4+3]);
    }
  }
  if (tid < 64) {
    int n = nb0 + tid;
    if (n < N) {
      el[n] = (sE[tid*8+0] + sE[tid*8+1]) + (sE[tid*8+2] + sE[tid*8+3]);
      er[n] = (sE[tid*8+4] + sE[tid*8+5]) + (sE[tid*8+6] + sE[tid*8+7]);
    }
  }
}

// ---- edge softmax + aggregate: one wave per dst node, lane = feature ----
__global__ __launch_bounds__(256) void k_aggr(const float* __restrict__ feat,
                                              const float* __restrict__ el,
                                              const float* __restrict__ er,
                                              const int* __restrict__ row_ptr,
                                              const int* __restrict__ csr_src,
                                              unsigned char* __restrict__ mask,
                                              int write_mask, int use_mask,
                                              float* __restrict__ hout, int N) {
  __shared__ __align__(16) int   su[4][64];
  __shared__ __align__(16) float spl[4][64];
  int wv = (int)((blockIdx.x * blockDim.x + threadIdx.x) >> 6);
  int wave = threadIdx.x >> 6, lane = threadIdx.x & 63;
  if (wv >= N) return;
  int beg = row_ptr[wv], end = row_ptr[wv + 1];
  int deg = end - beg;
  float erv = er[wv];
  float acc0 = 0.f, acc1 = 0.f, acc2 = 0.f, acc3 = 0.f;
  if (deg <= 64) {
    int k = beg + lane;
    bool have = (lane < deg);
    int u = have ? csr_src[k] : 0;
    float sc = -INFINITY;
    if (have) {
      float e0 = el[u] + erv;
      sc = (e0 >= 0.f) ? e0 : 0.2f * e0;
      if (use_mask && mask[k] == 0) sc = -1e9f;
    }
    float m = sc;
    #pragma unroll
    for (int off = 32; off; off >>= 1) m = fmaxf(m, __shfl_xor(m, off, 64));
    float pl = have ? expf(sc - m) : 0.f;
    float s = pl;
    #pragma unroll
    for (int off = 32; off; off >>= 1) s += __shfl_xor(s, off, 64);
    pl *= 1.0f / fmaxf(s, 1e-9f);
    if (write_mask && have) mask[k] = (pl >= 0.01f) ? 1 : 0;
    su[wave][lane] = u;
    spl[wave][lane] = pl;
    int dq = (deg + 3) >> 2;
    #pragma unroll 2
    for (int q = 0; q < dq; q++) {
      int4   uu = *(const int4*)&su[wave][q * 4];
      float4 pp = *(const float4*)&spl[wave][q * 4];
      acc0 = fmaf(pp.x, feat[(size_t)uu.x * 64 + lane], acc0);
      acc1 = fmaf(pp.y, feat[(size_t)uu.y * 64 + lane], acc1);
      acc2 = fmaf(pp.z, feat[(size_t)uu.z * 64 + lane], acc2);
      acc3 = fmaf(pp.w, feat[(size_t)uu.w * 64 + lane], acc3);
    }
  } else {
    float m = -INFINITY, s = 0.f;
    for (int base = beg; base < end; base += 64) {
      int k = base + lane;
      float sc = -INFINITY;
      if (k < end) {
        int u = csr_src[k];
        float e0 = el[u] + erv;
        sc = (e0 >= 0.f) ? e0 : 0.2f * e0;
        if (use_mask && mask[k] == 0) sc = -1e9f;
      }
      float cm = sc;
      #pragma unroll
      for (int off = 32; off; off >>= 1) cm = fmaxf(cm, __shfl_xor(cm, off, 64));
      float nm = fmaxf(m, cm);
      float t = (k < end) ? expf(sc - nm) : 0.f;
      #pragma unroll
      for (int off = 32; off; off >>= 1) t += __shfl_xor(t, off, 64);
      s = s * expf(m - nm) + t;
      m = nm;
    }
    float inv = 1.0f / fmaxf(s, 1e-9f);
    for (int base = beg; base < end; base += 64) {
      int k = base + lane;
      int u = 0;
      float pl = 0.f;
      if (k < end) {
        u = csr_src[k];
        float e0 = el[u] + erv;
        float sc = (e0 >= 0.f) ? e0 : 0.2f * e0;
        if (use_mask && mask[k] == 0) sc = -1e9f;
        pl = expf(sc - m) * inv;
        if (write_mask) mask[k] = (pl >= 0.01f) ? 1 : 0;
      }
      su[wave][lane] = u;
      spl[wave][lane] = pl;
      int cnt = min(64, end - base);
      int dq = (cnt + 3) >> 2;
      for (int q = 0; q < dq; q++) {
        int4   uu = *(const int4*)&su[wave][q * 4];
        float4 pp = *(const float4*)&spl[wave][q * 4];
        acc0 = fmaf(pp.x, feat[(size_t)uu.x * 64 + lane], acc0);
        acc1 = fmaf(pp.y, feat[(size_t)uu.y * 64 + lane], acc1);
        acc2 = fmaf(pp.z, feat[(size_t)uu.z * 64 + lane], acc2);
        acc3 = fmaf(pp.w, feat[(size_t)uu.w * 64 + lane], acc3);
      }
    }
  }
  float acc = (acc0 + acc1) + (acc2 + acc3);
  hout[(size_t)wv * 64 + lane] = (acc > 0.f) ? acc : expm1f(acc);
}

// ---- fused MLP head: block=64 nodes ----
__global__ __launch_bounds__(256, 3) void k_mlp(const float* __restrict__ o0,
                                                const float* __restrict__ o1,
                                                const float* __restrict__ o2,
                                                const float* __restrict__ o3,
                                                const float* __restrict__ W0,
                                                const float* __restrict__ b0,
                                                const float* __restrict__ W1,
                                                const float* __restrict__ b1,
                                                const float* __restrict__ W2,
                                                const float* __restrict__ b2,
                                                float* __restrict__ out, int N) {
  __shared__ float sA[64 * 65];   // staged seg acts; reused as L0-out exchange
  __shared__ float sW[64 * SWS];  // W0 seg / W1 slot
  __shared__ float sR[64 * 5];    // layer-2 partials [node][wave]
  int tid = threadIdx.x, lane = tid & 63, wv = tid >> 6;
  int nb0 = blockIdx.x * 64;
  int nl = N - 1;
  int r = tid >> 2, p = tid & 3;
  int nr = lane >> 2, fc = lane & 3;
  int fq = wv * 16 + fc * 4;
  float acc[4][4];
  {
    float4 b0v = *(const float4*)(b0 + fq);
    #pragma unroll
    for (int m = 0; m < 4; m++) {
      acc[m][0] = b0v.x; acc[m][1] = b0v.y;
      acc[m][2] = b0v.z; acc[m][3] = b0v.w;
    }
  }

  auto seg = [&](const float* __restrict__ sp, const float* __restrict__ wp) {
    __syncthreads();   // prior iter's sA/sW reads complete before restage
    {
      const float* g = sp + (size_t)min(nb0 + r, nl) * 64 + p * 16;
      float4 v0 = *(const float4*)(g + 0), v1 = *(const float4*)(g + 4);
      float4 v2 = *(const float4*)(g + 8), v3 = *(const float4*)(g + 12);
      float* dp = &sA[r * 65 + p * 16];
      dp[0]=v0.x; dp[1]=v0.y; dp[2]=v0.z; dp[3]=v0.w;
      dp[4]=v1.x; dp[5]=v1.y; dp[6]=v1.z; dp[7]=v1.w;
      dp[8]=v2.x; dp[9]=v2.y; dp[10]=v2.z; dp[11]=v2.w;
      dp[12]=v3.x; dp[13]=v3.y; dp[14]=v3.z; dp[15]=v3.w;
    }
    STAGE_W(sW, wp);
    __syncthreads();
    GEMM64(acc, sA, 65, 0);
  };
  seg(o0, W0);
  seg(o1, W0 + 64 * 64);
  seg(o2, W0 + 128 * 64);
  seg(o3, W0 + 192 * 64);

  // layer-0 relu -> cross-wave exchange (reuse sA), stage W1
  __syncthreads();
  STAGE_W(sW, W1);
  #pragma unroll
  for (int m = 0; m < 4; m++)
    #pragma unroll
    for (int j = 0; j < 4; j++) {
      float z = acc[m][j];
      sA[(nr + 16 * m) * 65 + fq + j] = (z > 0.f) ? z : 0.f;
    }
  __syncthreads();
  float a1[4][4];
  {
    float4 b1v = *(const float4*)(b1 + fq);
    #pragma unroll
    for (int m = 0; m < 4; m++) {
      a1[m][0] = b1v.x; a1[m][1] = b1v.y;
      a1[m][2] = b1v.z; a1[m][3] = b1v.w;
    }
  }
  GEMM64(a1, sA, 65, 0);
  {
    float4 w2v = *(const float4*)(W2 + fq);
    float w2a[4] = {w2v.x, w2v.y, w2v.z, w2v.w};
    #pragma unroll
    for (int m = 0; m < 4; m++) {
      float rp = 0.f;
      #pragma unroll
      for (int j = 0; j < 4; j++) {
        float t = (a1[m][j] > 0.f) ? a1[m][j] : 0.f;
        rp = fmaf(t, w2a[j], rp);
      }
      rp += __shfl_xor(rp, 1, 64); rp += __shfl_xor(rp, 2, 64);
      if (fc == 0) sR[(nr + 16 * m) * 5 + wv] = rp;
    }
  }
  __syncthreads();
  if (tid < 64) {
    int n = nb0 + tid;
    if (n < N) {
      float o = (sR[tid*5+0] + sR[tid*5+1]) + (sR[tid*5+2] + sR[tid*5+3]) + b2[0];
      out[n] = (o > 0.f) ? o : 0.f;
    }
  }
}

extern "C" void kernel_launch(void* const* d_in, const int* in_sizes, int n_in,
                              void* d_out, int out_size, void* d_ws, size_t ws_size,
                              hipStream_t stream) {
  const float* x       = (const float*)d_in[0];
  const int*   esrc    = (const int*)d_in[1];
  const int*   edst    = (const int*)d_in[2];
  const float* W_embed = (const float*)d_in[3];
  const float* W_gat   = (const float*)d_in[4];
  const float* a_l     = (const float*)d_in[5];
  const float* a_r     = (const float*)d_in[6];
  const float* W0      = (const float*)d_in[7];
  const float* b0      = (const float*)d_in[8];
  const float* W1      = (const float*)d_in[9];
  const float* b1      = (const float*)d_in[10];
  const float* W2      = (const float*)d_in[11];
  const float* b2      = (const float*)d_in[12];
  float* out = (float*)d_out;
  const int N = in_sizes[0] / 128;
  const int E = in_sizes[1];

  char* p = (char*)d_ws;
  auto alloc = [&](size_t bytes) -> char* {
    char* r = p;
    p += (bytes + 255) & ~(size_t)255;
    return r;
  };
  float* out0 = (float*)alloc((size_t)N * 64 * 4);
  float* out1 = (float*)alloc((size_t)N * 64 * 4);
  float* out2 = (float*)alloc((size_t)N * 64 * 4);
  float* out3 = (float*)alloc((size_t)N * 64 * 4);
  float* feat = (float*)alloc((size_t)N * 64 * 4);
  float* el   = (float*)alloc((size_t)N * 4);
  float* er   = (float*)alloc((size_t)N * 4);
  int* counts  = (int*)alloc((size_t)N * 4);
  int* row_ptr = (int*)alloc((size_t)(N + 1) * 4);
  int* csr_src = (int*)alloc((size_t)E * 4);
  unsigned char* mask = (unsigned char*)alloc((size_t)E);
  int nb = (N + 1023) / 1024;
  int* bsum = (int*)alloc((size_t)nb * 4);
  int* bofs = (int*)alloc((size_t)nb * 4);
  // counting-sort workspace
  int nbuk = (N + 127) >> 7;
  int nbg = nbuk * 8;
  int* cntA = (int*)alloc((size_t)nbg * 4);
  int* ofsA = (int*)alloc((size_t)(nbg + 1) * 4);
  int* curA = (int*)alloc((size_t)nbg * 4);
  int2* tmp = (int2*)alloc((size_t)E * 8);

  // --- CSR build (dst-sorted), counting-sort version ---
  k_zero<<<(N + 255) / 256, 256, 0, stream>>>(counts, cntA, N, nbg);
  k_hist2<<<(E + 255) / 256, 256, 0, stream>>>(edst, counts, cntA, E);
  k_bsum<<<nb, 1024, 0, stream>>>(counts, bsum, N);
  k_bscan<<<1, 64, 0, stream>>>(bsum, bofs, row_ptr, nb, N);
  k_scan3<<<nb, 1024, 0, stream>>>(counts, bofs, row_ptr, N);
  k_scanA<<<1, 64, 0, stream>>>(cntA, ofsA, curA, nbg, E);
  k_bin<<<(E + 1023) / 1024, 256, 0, stream>>>(esrc, edst, curA, tmp, E);
  k_csr<<<nbuk, 256, 0, stream>>>(tmp, ofsA, row_ptr, csr_src, N, nbuk);

  // --- dense grid: 64 nodes per 256-thread block ---
  int dgb = (N + 63) / 64;

  // --- layer 0: fused embed + feat ---
  k_embed_feat<<<dgb, 256, 0, stream>>>(x, W_embed, W_gat,
                                        a_l, a_r, feat, el, er, N);
  float* outs[4] = {out0, out1, out2, out3};
  k_aggr<<<(N + 3) / 4, 256, 0, stream>>>(feat, el, er, row_ptr, csr_src, mask,
                                          1, 0, out0, N);

  // --- layers 1..3 ---
  for (int l = 1; l < 4; l++) {
    k_feat<<<dgb, 256, 0, stream>>>(outs[l - 1], W_gat + (size_t)l * 4096,
                                    a_l + (size_t)l * 64, a_r + (size_t)l * 64,
                                    feat, el, er, N);
    k_aggr<<<(N + 3) / 4, 256, 0, stream>>>(feat, el, er, row_ptr, csr_src, mask,
                                            0, 1, outs[l], N);
  }

  // --- MLP head ---
  k_mlp<<<dgb, 256, 0, stream>>>(out0, out1, out2, out3, W0, b0,
                                 W1, b1, W2, b2, out, N);
}